// Round 5
// baseline (222.903 us; speedup 1.0000x reference)
//
#include <hip/hip_runtime.h>
#include <hip/hip_bf16.h>

// MDCA: for each of 4 CAMs [B=128, C=1000, H=14, W=14]:
//   avg_conf[c]  = mean over (b,h,w) of cam[b,c,h,w]
//   avg_count[c] = bincount(target, C)[c] / B
//   out[cam] = mean_c |avg_conf[c] - avg_count[c]|
//
// R4: R0's stage-1 (fastest measured: 4 structurally different variants all
// hit the same ~5.6 TB/s blended read ceiling; pattern-insensitive), with
// the finalize FUSED via last-block ticket: saves the second launch + drain
// gap (~3-4 us). Sums are written exactly once per (c,cam) -> deterministic;
// ticket winner varies but computes an order-fixed reduction -> bit-stable.
// Ticket zeroed each call by 4-byte hipMemsetAsync (graph-capture legal).

constexpr int B    = 128;
constexpr int C    = 1000;
constexpr int HW   = 196;   // 14*14
constexpr int HW4  = 49;    // float4 per (b,c) segment
constexpr int NBLK = C * 4; // total blocks

__global__ __launch_bounds__(256) void mdca_fused_kernel(
    const float* __restrict__ c0, const float* __restrict__ c1,
    const float* __restrict__ c2, const float* __restrict__ c3,
    const int* __restrict__ target, float* __restrict__ out,
    float* __restrict__ sums, unsigned int* __restrict__ ticket)
{
    const int c   = blockIdx.x;
    const int cam = blockIdx.y;
    const int tid = threadIdx.x;
    const float* __restrict__ src =
        (cam == 0) ? c0 : (cam == 1) ? c1 : (cam == 2) ? c2 : c3;

    // ---- phase 1: sum cam[b, c, :, :] over b (R0 structure, unchanged) ----
    float acc = 0.0f;
    const int total4 = B * HW4;  // 6272
    for (int i = tid; i < total4; i += 256) {
        const int b = i / HW4;           // magic-mul division
        const int j = i - b * HW4;
        const float4 v = *reinterpret_cast<const float4*>(
            src + (size_t)(b * C + c) * HW + (size_t)j * 4);
        acc += (v.x + v.y) + (v.z + v.w);
    }

    #pragma unroll
    for (int off = 32; off > 0; off >>= 1)
        acc += __shfl_down(acc, off, 64);

    __shared__ float red[4];
    __shared__ unsigned int last;
    const int wid  = tid >> 6;
    const int lane = tid & 63;
    if (lane == 0) red[wid] = acc;
    __syncthreads();
    if (tid == 0) {
        sums[cam * C + c] = (red[0] + red[1]) + (red[2] + red[3]);
        __threadfence();                       // release: L2 writeback
        last = atomicAdd(ticket, 1u);
    }
    __syncthreads();
    if (last != (unsigned int)(NBLK - 1)) return;

    // ---- phase 2: last block finalizes all 4 cams (16 KB of sums) ----
    __threadfence();                           // acquire: invalidate stale

    __shared__ int   cnt[C];
    __shared__ float red4[4][4];
    for (int i = tid; i < C; i += 256) cnt[i] = 0;
    __syncthreads();
    if (tid < B) atomicAdd(&cnt[target[tid]], 1);
    __syncthreads();

    const float inv_BHW = 1.0f / (float)(B * HW);
    const float inv_B   = 1.0f / (float)B;

    float a0 = 0.0f, a1 = 0.0f, a2 = 0.0f, a3 = 0.0f;
    for (int cc = tid; cc < C; cc += 256) {
        const float n = (float)cnt[cc] * inv_B;
        a0 += fabsf(sums[0 * C + cc] * inv_BHW - n);
        a1 += fabsf(sums[1 * C + cc] * inv_BHW - n);
        a2 += fabsf(sums[2 * C + cc] * inv_BHW - n);
        a3 += fabsf(sums[3 * C + cc] * inv_BHW - n);
    }

    #pragma unroll
    for (int off = 32; off > 0; off >>= 1) {
        a0 += __shfl_down(a0, off, 64);
        a1 += __shfl_down(a1, off, 64);
        a2 += __shfl_down(a2, off, 64);
        a3 += __shfl_down(a3, off, 64);
    }
    if (lane == 0) {
        red4[wid][0] = a0; red4[wid][1] = a1;
        red4[wid][2] = a2; red4[wid][3] = a3;
    }
    __syncthreads();
    if (tid < 4) {
        const float s = ((red4[0][tid] + red4[1][tid]) +
                         (red4[2][tid] + red4[3][tid]));
        out[tid] = s * (1.0f / (float)C);
    }
}

extern "C" void kernel_launch(void* const* d_in, const int* in_sizes, int n_in,
                              void* d_out, int out_size, void* d_ws, size_t ws_size,
                              hipStream_t stream) {
    const float* c0 = (const float*)d_in[0];
    const float* c1 = (const float*)d_in[1];
    const float* c2 = (const float*)d_in[2];
    const float* c3 = (const float*)d_in[3];
    const int*   target = (const int*)d_in[4];

    float*        sums   = (float*)d_ws;                        // 16,000 B
    unsigned int* ticket = (unsigned int*)((char*)d_ws + 16384);

    hipMemsetAsync(ticket, 0, sizeof(unsigned int), stream);

    dim3 grid(C, 4);
    mdca_fused_kernel<<<grid, 256, 0, stream>>>(
        c0, c1, c2, c3, target, (float*)d_out, sums, ticket);
}

// Round 6
// 75.156 us; speedup vs baseline: 2.9659x; 2.9659x over previous
//
#include <hip/hip_runtime.h>
#include <hip/hip_bf16.h>

// MDCA: for each of 4 CAMs [B=128, C=1000, H=14, W=14]:
//   avg_conf[c]  = mean over (b,h,w) of cam[b,c,h,w]
//   avg_count[c] = bincount(target, C)[c] / B
//   out[cam] = mean_c |avg_conf[c] - avg_count[c]|
//
// R5 = R0 (best measured, 76 us) + 4-deep MLP unroll in stage 1.
// R4's fused variant regressed 3x: per-block device-scope __threadfence
// forces per-XCD L2 writeback/invalidate (L2s aren't the coherence point
// across XCDs) -> 4000 L2 flushes halved the read rate. Two kernels it is.
// R0's VGPR=8 showed only ONE float4 in flight per thread; unrolling with
// 4 independent addresses + accumulators raises memory-level parallelism.

constexpr int B   = 128;
constexpr int C   = 1000;
constexpr int HW  = 196;   // 14*14
constexpr int HW4 = 49;    // float4 per (b,c) segment

// One block per (class c = blockIdx.x, cam = blockIdx.y).
// Sums cam[b, c, :, :] over all b, writes sums[cam*C + c].
__global__ __launch_bounds__(256) void class_sum_kernel(
    const float* __restrict__ c0, const float* __restrict__ c1,
    const float* __restrict__ c2, const float* __restrict__ c3,
    float* __restrict__ sums)
{
    const int c   = blockIdx.x;
    const int cam = blockIdx.y;
    const int tid = threadIdx.x;
    const float* __restrict__ src =
        (cam == 0) ? c0 : (cam == 1) ? c1 : (cam == 2) ? c2 : c3;

    // flat index i in [0, B*HW4): b = i/49, j = i%49;
    // element addr = (b*C + c)*HW + j*4  (float4-aligned, 784 = 16*49)
    float a0 = 0.0f, a1 = 0.0f, a2 = 0.0f, a3 = 0.0f;

    int i = tid;
    #pragma unroll
    for (int g = 0; g < 6; ++g) {          // 6 * 1024 = 6144 of 6272
        const int i0 = i, i1 = i + 256, i2 = i + 512, i3 = i + 768;
        const int b0 = i0 / HW4, j0 = i0 - b0 * HW4;
        const int b1 = i1 / HW4, j1 = i1 - b1 * HW4;
        const int b2 = i2 / HW4, j2 = i2 - b2 * HW4;
        const int b3 = i3 / HW4, j3 = i3 - b3 * HW4;
        const float4 v0 = *reinterpret_cast<const float4*>(
            src + (size_t)(b0 * C + c) * HW + (size_t)j0 * 4);
        const float4 v1 = *reinterpret_cast<const float4*>(
            src + (size_t)(b1 * C + c) * HW + (size_t)j1 * 4);
        const float4 v2 = *reinterpret_cast<const float4*>(
            src + (size_t)(b2 * C + c) * HW + (size_t)j2 * 4);
        const float4 v3 = *reinterpret_cast<const float4*>(
            src + (size_t)(b3 * C + c) * HW + (size_t)j3 * 4);
        a0 += (v0.x + v0.y) + (v0.z + v0.w);
        a1 += (v1.x + v1.y) + (v1.z + v1.w);
        a2 += (v2.x + v2.y) + (v2.z + v2.w);
        a3 += (v3.x + v3.y) + (v3.z + v3.w);
        i += 1024;
    }
    // tail: i = tid + 6144; active for tid < 128 (6272 - 6144)
    if (i < B * HW4) {
        const int b = i / HW4, j = i - b * HW4;
        const float4 v = *reinterpret_cast<const float4*>(
            src + (size_t)(b * C + c) * HW + (size_t)j * 4);
        a0 += (v.x + v.y) + (v.z + v.w);
    }

    float acc = (a0 + a1) + (a2 + a3);
    #pragma unroll
    for (int off = 32; off > 0; off >>= 1)
        acc += __shfl_down(acc, off, 64);

    __shared__ float red[4];
    const int wid  = tid >> 6;
    const int lane = tid & 63;
    if (lane == 0) red[wid] = acc;
    __syncthreads();
    if (tid == 0)
        sums[cam * C + c] = (red[0] + red[1]) + (red[2] + red[3]);
}

// One block per cam. LDS histogram (deterministic int atomics), then
// block-reduce |avg_conf - avg_count| over C classes.
__global__ __launch_bounds__(1024) void finalize_kernel(
    const float* __restrict__ sums, const int* __restrict__ target,
    float* __restrict__ out)
{
    __shared__ int   cnt[C];
    __shared__ float red[16];

    const int cam = blockIdx.x;
    const int tid = threadIdx.x;

    for (int i = tid; i < C; i += 1024) cnt[i] = 0;
    __syncthreads();
    if (tid < B) atomicAdd(&cnt[target[tid]], 1);
    __syncthreads();

    const float inv_BHW = 1.0f / (float)(B * HW);
    const float inv_B   = 1.0f / (float)B;

    float acc = 0.0f;
    for (int cc = tid; cc < C; cc += 1024) {
        const float avg_conf  = sums[cam * C + cc] * inv_BHW;
        const float avg_count = (float)cnt[cc] * inv_B;
        acc += fabsf(avg_conf - avg_count);
    }

    #pragma unroll
    for (int off = 32; off > 0; off >>= 1)
        acc += __shfl_down(acc, off, 64);
    if ((tid & 63) == 0) red[tid >> 6] = acc;
    __syncthreads();
    if (tid == 0) {
        float s = 0.0f;
        #pragma unroll
        for (int w = 0; w < 16; ++w) s += red[w];
        out[cam] = s * (1.0f / (float)C);
    }
}

extern "C" void kernel_launch(void* const* d_in, const int* in_sizes, int n_in,
                              void* d_out, int out_size, void* d_ws, size_t ws_size,
                              hipStream_t stream) {
    const float* c0 = (const float*)d_in[0];
    const float* c1 = (const float*)d_in[1];
    const float* c2 = (const float*)d_in[2];
    const float* c3 = (const float*)d_in[3];
    const int*   target = (const int*)d_in[4];

    float* sums = (float*)d_ws;  // 4*1000 floats, fully overwritten each call

    dim3 grid1(C, 4);
    class_sum_kernel<<<grid1, 256, 0, stream>>>(c0, c1, c2, c3, sums);
    finalize_kernel<<<4, 1024, 0, stream>>>(sums, target, (float*)d_out);
}